// Round 2
// baseline (305.348 us; speedup 1.0000x reference)
//
#include <hip/hip_runtime.h>

// Maxwell model: gamma_{n+1} = gamma_n + dt_n * 2 * (eps_n - gamma_n)
//              = (1 - 2 dt_n) gamma_n + 2 dt_n eps_n   (linear recurrence)
// sigma_t = E_INFTY*eps_t + E*(eps_t - gamma_t) = 3*eps_t - 2*gamma_t, sigma_0 = 0.
//
// One block (256 threads) per row of T=2048. Each thread owns 8 contiguous
// timesteps: coalesced float4 loads, local (P,Q) composition, block-wide
// associative scan (shfl within wave + LDS across 4 waves), sequential replay,
// coalesced float4 stores.

#define T_LEN 2048

__global__ __launch_bounds__(256) void maxwell_scan_kernel(
    const float* __restrict__ eps_g, const float* __restrict__ dt_g,
    float* __restrict__ out_g)
{
    const int row = blockIdx.x;
    const int tid = threadIdx.x;
    const long base = (long)row * T_LEN + (long)tid * 8;

    const float4 e0 = *(const float4*)(eps_g + base);
    const float4 e1 = *(const float4*)(eps_g + base + 4);
    const float4 d0 = *(const float4*)(dt_g + base);
    const float4 d1 = *(const float4*)(dt_g + base + 4);

    float e[8] = {e0.x, e0.y, e0.z, e0.w, e1.x, e1.y, e1.z, e1.w};
    float d[8] = {d0.x, d0.y, d0.z, d0.w, d1.x, d1.y, d1.z, d1.w};

    // Compose this thread's 8 transitions: g -> P*g + Q
    float P = 1.0f, Q = 0.0f;
    #pragma unroll
    for (int k = 0; k < 8; ++k) {
        const float ad = 2.0f * d[k];
        const float A  = 1.0f - ad;
        const float Bv = ad * e[k];
        Q = A * Q + Bv;   // apply transition k after accumulated (P,Q)
        P = A * P;
    }

    // Inclusive scan within the 64-lane wave.
    const int lane = tid & 63;
    const int wid  = tid >> 6;
    #pragma unroll
    for (int dd = 1; dd < 64; dd <<= 1) {
        const float Pp = __shfl_up(P, dd);
        const float Qp = __shfl_up(Q, dd);
        if (lane >= dd) {
            Q = P * Qp + Q;   // combine(prev=(Pp,Qp), cur=(P,Q))
            P = P * Pp;
        }
    }

    // Cross-wave combine via LDS (4 waves).
    __shared__ float sP[4], sQ[4];
    if (lane == 63) { sP[wid] = P; sQ[wid] = Q; }
    __syncthreads();

    float Qw = 0.0f;  // Q of composition of waves [0, wid)
    for (int w = 0; w < wid; ++w) {
        Qw = sP[w] * Qw + sQ[w];
    }

    // Exclusive within wave: inclusive of lane-1 (identity at lane 0).
    float Pe = __shfl_up(P, 1);
    float Qe = __shfl_up(Q, 1);
    if (lane == 0) { Pe = 1.0f; Qe = 0.0f; }

    // gamma at t = tid*8, starting from gamma_0 = 0: only Q survives.
    float g = Pe * Qw + Qe;

    // Replay the 8 local steps with the true incoming gamma.
    float o[8];
    o[0] = 3.0f * e[0] - 2.0f * g;
    #pragma unroll
    for (int k = 1; k < 8; ++k) {
        g = g + 2.0f * d[k - 1] * (e[k - 1] - g);
        o[k] = 3.0f * e[k] - 2.0f * g;
    }
    if (tid == 0) o[0] = 0.0f;   // sigma_0 = 0

    float4 w0 = make_float4(o[0], o[1], o[2], o[3]);
    float4 w1 = make_float4(o[4], o[5], o[6], o[7]);
    *(float4*)(out_g + base)     = w0;
    *(float4*)(out_g + base + 4) = w1;
}

extern "C" void kernel_launch(void* const* d_in, const int* in_sizes, int n_in,
                              void* d_out, int out_size, void* d_ws, size_t ws_size,
                              hipStream_t stream) {
    const float* strains = (const float*)d_in[0];
    const float* dts     = (const float*)d_in[1];
    float* out           = (float*)d_out;

    const int B = in_sizes[0] / T_LEN;   // 16384 for the reference shape
    maxwell_scan_kernel<<<B, 256, 0, stream>>>(strains, dts, out);
}